// Round 3
// baseline (543.238 us; speedup 1.0000x reference)
//
#include <hip/hip_runtime.h>
#include <hip/hip_bf16.h>
#include <stdint.h>

// Problem constants
#define B_N 1024
#define S_N 65536
#define D_N 512
#define NS 32                 // s-chunks; grid = 8 batch-blocks x NS = 256 = 1 block/CU
#define SC (S_N / NS)         // 2048 s per block
#define SB 256                // s subtile (P tile = 128 b x 256 s in LDS)
#define NSUB (SC / SB)        // 8

typedef __attribute__((ext_vector_type(8))) short bf16x8;   // 8 bf16 in 4 VGPRs
typedef __attribute__((ext_vector_type(4))) float f32x4;

// ---- workspace layout (bytes) ----
#define OFF_MBF   ((size_t)0)                                  // M bf16 (s,d)   64 MiB
#define OFF_MT    (OFF_MBF + (size_t)S_N * D_N * 2)            // M^T bf16 (d,s) 64 MiB
#define OFF_XBF   (OFF_MT  + (size_t)D_N * S_N * 2)            // X bf16         1 MiB
#define OFF_RX    (OFF_XBF + (size_t)B_N * D_N * 2)            // 8*log2e*rsqrt(|x|^2)  4 KiB
#define OFF_RM    (OFF_RX  + (size_t)B_N * 4)                  // rsqrt(|m|^2)   256 KiB
#define OFF_LSUM  (OFF_RM  + (size_t)S_N * 4)                  // softmax denom  4 KiB
#define OFF_OPART (OFF_LSUM + (size_t)B_N * 4)                 // PV partials    64 MiB

__device__ __forceinline__ unsigned short f2bf(float f) {
  unsigned u = __builtin_bit_cast(unsigned, f);
  u += 0x7fffu + ((u >> 16) & 1u);          // RNE
  return (unsigned short)(u >> 16);
}

__device__ __forceinline__ void stage16(const unsigned short* g, unsigned short* l) {
  // async global->LDS, 16B/lane; LDS dest is wave-uniform base + lane*16
  __builtin_amdgcn_global_load_lds(
      (const __attribute__((address_space(1))) void*)g,
      (__attribute__((address_space(3))) void*)l, 16, 0, 0);
}

// ---------------- prep X: bf16 convert + rx = 8*log2e*rsqrt(||x||^2) ----------------
__global__ void k_prep_x(const float* __restrict__ X, unsigned short* __restrict__ Xbf,
                         float* __restrict__ rx) {
  const int row = blockIdx.x;
  const int t = threadIdx.x;  // 0..127
  float4 v = ((const float4*)(X + (size_t)row * D_N))[t];
  float ss = v.x*v.x + v.y*v.y + v.z*v.z + v.w*v.w;
  ushort4 o; o.x = f2bf(v.x); o.y = f2bf(v.y); o.z = f2bf(v.z); o.w = f2bf(v.w);
  ((ushort4*)(Xbf + (size_t)row * D_N))[t] = o;
  #pragma unroll
  for (int m = 1; m < 64; m <<= 1) ss += __shfl_xor(ss, m);
  __shared__ float partial[2];
  if ((t & 63) == 0) partial[t >> 6] = ss;
  __syncthreads();
  if (t == 0) rx[row] = 11.541560327111707f * rsqrtf(fmaxf(partial[0] + partial[1], 1e-24f));
}

// ------- prep M: bf16 convert, LDS-transpose to Mt, rm = rsqrt(||m||^2) -------
__global__ void k_prep_m(const float* __restrict__ M, unsigned short* __restrict__ Mbf,
                         unsigned short* __restrict__ Mt, float* __restrict__ rm) {
  __shared__ float ts[64 * 65];             // 64x64 tile, +1 pad -> conflict-free transpose
  const int t = threadIdx.x;                // 256
  const int s0 = blockIdx.x * 64;
  const int r = t >> 2, cq = t & 3;
  const int c = t >> 2, sq = t & 3;
  float ss = 0.f;
  for (int ct = 0; ct < 8; ++ct) {
    float f[16];
    const float4* src = (const float4*)(M + (size_t)(s0 + r) * D_N + ct * 64 + cq * 16);
    #pragma unroll
    for (int k = 0; k < 4; ++k) {
      float4 v = src[k];
      f[4*k+0] = v.x; f[4*k+1] = v.y; f[4*k+2] = v.z; f[4*k+3] = v.w;
    }
    union { unsigned short u[16]; uint4 v4[2]; } pk;
    #pragma unroll
    for (int j = 0; j < 16; ++j) {
      ss += f[j] * f[j];
      pk.u[j] = f2bf(f[j]);
      ts[r * 65 + cq * 16 + j] = f[j];
    }
    uint4* dst = (uint4*)(Mbf + (size_t)(s0 + r) * D_N + ct * 64 + cq * 16);
    dst[0] = pk.v4[0]; dst[1] = pk.v4[1];
    __syncthreads();
    union { unsigned short u[16]; uint4 v4[2]; } pt;
    #pragma unroll
    for (int j = 0; j < 16; ++j) pt.u[j] = f2bf(ts[(sq * 16 + j) * 65 + c]);
    uint4* dt = (uint4*)(Mt + (size_t)(ct * 64 + c) * S_N + s0 + sq * 16);
    dt[0] = pt.v4[0]; dt[1] = pt.v4[1];
    __syncthreads();
  }
  ss += __shfl_xor(ss, 1);
  ss += __shfl_xor(ss, 2);
  if (cq == 0) rm[s0 + r] = rsqrtf(fmaxf(ss, 1e-24f));
}

// ================= fused QK -> exp -> PV, 64x64 wave tiles, SB=256 =================
// QK: P^T tile 256s x 128b, wave grid 4s x 2b, wave tile 64x64 (4x4 frags of
// 16x16x32 -> 8 ds_read_b128 per 16 MFMA, 1.5x the FLOP/LDS-byte of R2).
// PV: O 128b x 512d, wave grid 2b x 4d, per wave 64b x 128d (2 d-groups).
// LDS: M/Mt double-buffer 2x32KB + P region 64KB. During QK the P region's
// first 32KB doubles as the X staging dbuf (P not yet written) -> fits 128KB.
// Pipeline: counted vmcnt (QK phase = 6 loads/thread, PV = 4), never 0 except
// the final phase; X for next sub issued after PV's last barrier (P region free).
__global__ __launch_bounds__(512, 2) void k_fused(
    const unsigned short* __restrict__ Xbf, const unsigned short* __restrict__ Mbf,
    const unsigned short* __restrict__ Mt, const float* __restrict__ rx,
    const float* __restrict__ rminv, float* __restrict__ lsum,
    float* __restrict__ Opart) {
  __shared__ unsigned short Mb[2][16384];   // 2 x 32 KiB: M [256][64] (QK) / Mt [256][64] (PV)
  __shared__ unsigned short Ps[32768];      // 64 KiB: P [128][256] swizzled; X dbuf 2x16KB in QK

  const int t = threadIdx.x;               // 0..511
  const int w = t >> 6, lane = t & 63, quad = lane >> 4, l15 = lane & 15;
  const int qs = w >> 1, qcb = w & 1;      // QK wave grid: 4 s-slices x 2 b-halves
  const int qb = w >> 2, qd = w & 3;       // PV wave grid: 2 b-halves x 4 d-slices
  const int x7 = l15 & 7;

  // XCD swizzle: 8 batch-blocks sharing an s-chunk land on one XCD
  const int bid = blockIdx.x;
  const int xcd = bid & 7, slot = bid >> 3;
  const int bblk = slot & 7;
  const int chunk = xcd * 4 + (slot >> 3);
  const int b0 = bblk * 128;
  const int s0 = chunk * SC;

  f32x4 accO[2][4][4];                     // O accumulator: (d-group, i, j) = 128 VGPR
  #pragma unroll
  for (int g = 0; g < 2; ++g)
    #pragma unroll
    for (int i = 0; i < 4; ++i)
      #pragma unroll
      for (int j = 0; j < 4; ++j) accO[g][i][j] = (f32x4){0.f, 0.f, 0.f, 0.f};

  float ls[4] = {0.f, 0.f, 0.f, 0.f};
  float rxj[4];
  #pragma unroll
  for (int j = 0; j < 4; ++j) rxj[j] = rx[b0 + qcb * 64 + j * 16 + l15];

  // stager roles: 64 rows x 8 chunks per issue; source-side inverse swizzle
  const int srow8 = t >> 3;
  const int sch8  = ((t & 7) ^ (srow8 & 7)) * 8;
  const unsigned short* gX = Xbf + (size_t)(b0 + srow8) * D_N + sch8;
  const unsigned short* gM = Mbf + (size_t)srow8 * D_N + sch8;
  const unsigned short* gT = Mt  + (size_t)srow8 * S_N + sch8;
  unsigned short* MbU = &Mb[0][0];

  #define ISS_M(sS_, k0_, bi_) do {                                           \
    _Pragma("unroll")                                                         \
    for (int is = 0; is < 4; ++is)                                            \
      stage16(gM + (size_t)((sS_) + is * 64) * D_N + (k0_),                   \
              MbU + (bi_) * 16384 + is * 4096 + w * 512);                     \
  } while (0)
  #define ISS_X(k0_, bi_) do {                                                \
    _Pragma("unroll")                                                         \
    for (int is = 0; is < 2; ++is)                                            \
      stage16(gX + (size_t)(is * 64) * D_N + (k0_),                           \
              Ps + (bi_) * 8192 + is * 4096 + w * 512);                       \
  } while (0)
  #define ISS_T(sS_, p_, bi_) do {                                            \
    _Pragma("unroll")                                                         \
    for (int is = 0; is < 4; ++is)                                            \
      stage16(gT + (size_t)(((p_) >> 2) * 256 + is * 64) * S_N + (sS_) + (((p_) & 3) * 64), \
              MbU + (bi_) * 16384 + is * 4096 + w * 512);                     \
  } while (0)

  // prologue: sub 0, QK phase 0 into buffer 0 (M 4 + X 2 loads)
  ISS_M(s0, 0, 0);
  ISS_X(0, 0);

  for (int sub = 0; sub < NSUB; ++sub) {
    const int sS = s0 + sub * SB;

    // ---------------- QK phases 0..7 (k0 = phase*64) ----------------
    f32x4 accP[4][4];
    #pragma unroll
    for (int i = 0; i < 4; ++i)
      #pragma unroll
      for (int j = 0; j < 4; ++j) accP[i][j] = (f32x4){0.f, 0.f, 0.f, 0.f};

    #pragma unroll
    for (int p = 0; p < 8; ++p) {
      const int bi = p & 1;
      if (p < 7) { ISS_M(sS, (p + 1) * 64, bi ^ 1); ISS_X((p + 1) * 64, bi ^ 1); }
      else       { ISS_T(sS, 0, 0); }
      if (p < 7) asm volatile("s_waitcnt vmcnt(6)" ::: "memory");
      else       asm volatile("s_waitcnt vmcnt(4)" ::: "memory");
      __builtin_amdgcn_s_barrier();
      const unsigned short* As = MbU + bi * 16384;
      const unsigned short* Xs = Ps + bi * 8192;
      __builtin_amdgcn_s_setprio(1);
      #pragma unroll
      for (int kk = 0; kk < 64; kk += 32) {
        const int c = (kk >> 3) + quad;
        bf16x8 a[4], b[4];
        #pragma unroll
        for (int i = 0; i < 4; ++i)
          a[i] = *(const bf16x8*)&As[(qs * 64 + i * 16 + l15) * 64 + ((c ^ x7) << 3)];
        #pragma unroll
        for (int j = 0; j < 4; ++j)
          b[j] = *(const bf16x8*)&Xs[(qcb * 64 + j * 16 + l15) * 64 + ((c ^ x7) << 3)];
        #pragma unroll
        for (int i = 0; i < 4; ++i)
          #pragma unroll
          for (int j = 0; j < 4; ++j)
            accP[i][j] = __builtin_amdgcn_mfma_f32_16x16x32_bf16(a[i], b[j], accP[i][j], 0, 0, 0);
      }
      __builtin_amdgcn_s_setprio(0);
      __builtin_amdgcn_s_barrier();
    }

    // ------------- epilogue: p = exp2(dot*rx_b*rm_s), rowsum, P -> LDS -------------
    // C layout: s = qs*64 + i*16 + quad*4 + r (4 consecutive), b = qcb*64 + j*16 + l15
    {
      #pragma unroll
      for (int i = 0; i < 4; ++i) {
        const float4 rm = *(const float4*)&rminv[sS + qs * 64 + i * 16 + quad * 4];
        const int c16 = qs * 8 + i * 2 + (quad >> 1);
        #pragma unroll
        for (int j = 0; j < 4; ++j) {
          const float p0 = exp2f(accP[i][j][0] * rxj[j] * rm.x);
          const float p1 = exp2f(accP[i][j][1] * rxj[j] * rm.y);
          const float p2 = exp2f(accP[i][j][2] * rxj[j] * rm.z);
          const float p3 = exp2f(accP[i][j][3] * rxj[j] * rm.w);
          ls[j] += (p0 + p1) + (p2 + p3);
          const int brow = qcb * 64 + j * 16 + l15;
          uint2 pk;
          pk.x = (unsigned)f2bf(p0) | ((unsigned)f2bf(p1) << 16);
          pk.y = (unsigned)f2bf(p2) | ((unsigned)f2bf(p3) << 16);
          *(uint2*)&Ps[brow * 256 + (((c16 ^ (brow & 7)) << 3) | ((quad & 1) << 2))] = pk;
        }
      }
      asm volatile("s_waitcnt lgkmcnt(0)" ::: "memory");
      __builtin_amdgcn_sched_barrier(0);
    }

    // ---------------- PV phases 0..7 (d-group = p>>2, s-window = (p&3)*64) ----------------
    #pragma unroll
    for (int p = 0; p < 8; ++p) {
      const int bi = p & 1;
      if (p < 7)                 { ISS_T(sS, p + 1, bi ^ 1); }
      else if (sub < NSUB - 1)   { ISS_M(sS + SB, 0, 0); }
      if (p == 7 && sub == NSUB - 1) asm volatile("s_waitcnt vmcnt(0)" ::: "memory");
      else                           asm volatile("s_waitcnt vmcnt(4)" ::: "memory");
      __builtin_amdgcn_s_barrier();
      const unsigned short* Ts = MbU + bi * 16384;
      const int dcg = p >> 2;
      __builtin_amdgcn_s_setprio(1);
      #pragma unroll
      for (int kk = 0; kk < 64; kk += 32) {
        const int cP = (((p & 3) * 64 + kk) >> 3) + quad;
        const int cT = (kk >> 3) + quad;
        bf16x8 pa[4], mb[4];
        #pragma unroll
        for (int i = 0; i < 4; ++i)
          pa[i] = *(const bf16x8*)&Ps[(qb * 64 + i * 16 + l15) * 256 + ((cP ^ x7) << 3)];
        #pragma unroll
        for (int j = 0; j < 4; ++j)
          mb[j] = *(const bf16x8*)&Ts[(qd * 64 + j * 16 + l15) * 64 + ((cT ^ x7) << 3)];
        #pragma unroll
        for (int i = 0; i < 4; ++i)
          #pragma unroll
          for (int j = 0; j < 4; ++j)
            accO[dcg][i][j] = __builtin_amdgcn_mfma_f32_16x16x32_bf16(pa[i], mb[j], accO[dcg][i][j], 0, 0, 0);
      }
      __builtin_amdgcn_s_setprio(0);
      __builtin_amdgcn_s_barrier();
    }

    // next sub's X stage into the (now free) P region — after PV's last barrier
    if (sub < NSUB - 1) { ISS_X(0, 0); }
  }

  // ---------------- write O partials (coalesced over d via l15) ----------------
  float* Od = Opart + (size_t)chunk * ((size_t)B_N * D_N);
  #pragma unroll
  for (int g = 0; g < 2; ++g)
    #pragma unroll
    for (int i = 0; i < 4; ++i)
      #pragma unroll
      for (int r = 0; r < 4; ++r) {
        const int bb = b0 + qb * 64 + i * 16 + quad * 4 + r;
        #pragma unroll
        for (int j = 0; j < 4; ++j) {
          const int d = g * 256 + qd * 64 + j * 16 + l15;
          Od[(size_t)bb * D_N + d] = accO[g][i][j][r];
        }
      }

  // ---------------- lsum: quad-reduce, cross-wave via LDS, one atomic per b ----------------
  __syncthreads();
  float* red = (float*)MbU;                  // 8 waves x 64 b-slots
  #pragma unroll
  for (int j = 0; j < 4; ++j) {
    float v = ls[j];
    v += __shfl_xor(v, 16);
    v += __shfl_xor(v, 32);
    if (lane < 16) red[w * 64 + j * 16 + lane] = v;
  }
  __syncthreads();
  if (t < 128) {
    const int qc2 = t >> 6, idx = t & 63;
    float s = red[(0 + qc2) * 64 + idx] + red[(2 + qc2) * 64 + idx] +
              red[(4 + qc2) * 64 + idx] + red[(6 + qc2) * 64 + idx];
    unsafeAtomicAdd(&lsum[b0 + t], s);
  }
  #undef ISS_M
  #undef ISS_X
  #undef ISS_T
}

// ---------------- combine: out = (sum_ks Opart) / lsum ----------------
__global__ void k_combine(const float* __restrict__ Opart, const float* __restrict__ lsum,
                          float* __restrict__ out) {
  const int idx = blockIdx.x * 256 + threadIdx.x;  // float4 index, 131072 total
  const int b = idx >> 7;
  float4 s = {0.f, 0.f, 0.f, 0.f};
  #pragma unroll
  for (int ks = 0; ks < NS; ++ks) {
    float4 v = ((const float4*)Opart)[(size_t)ks * (B_N * D_N / 4) + idx];
    s.x += v.x; s.y += v.y; s.z += v.z; s.w += v.w;
  }
  const float inv = 1.0f / lsum[b];
  s.x *= inv; s.y *= inv; s.z *= inv; s.w *= inv;
  ((float4*)out)[idx] = s;
}

extern "C" void kernel_launch(void* const* d_in, const int* in_sizes, int n_in,
                              void* d_out, int out_size, void* d_ws, size_t ws_size,
                              hipStream_t stream) {
  const float* X = (const float*)d_in[0];
  const float* M = (const float*)d_in[1];
  char* ws = (char*)d_ws;
  unsigned short* Mbf = (unsigned short*)(ws + OFF_MBF);
  unsigned short* Mt  = (unsigned short*)(ws + OFF_MT);
  unsigned short* Xbf = (unsigned short*)(ws + OFF_XBF);
  float* rxv  = (float*)(ws + OFF_RX);
  float* rmv  = (float*)(ws + OFF_RM);
  float* lsum = (float*)(ws + OFF_LSUM);
  float* Opart = (float*)(ws + OFF_OPART);

  hipMemsetAsync(lsum, 0, B_N * sizeof(float), stream);
  k_prep_x<<<dim3(B_N), 128, 0, stream>>>(X, Xbf, rxv);
  k_prep_m<<<dim3(S_N / 64), 256, 0, stream>>>(M, Mbf, Mt, rmv);
  k_fused<<<dim3(8 * NS), 512, 0, stream>>>(Xbf, Mbf, Mt, rxv, rmv, lsum, Opart);
  k_combine<<<dim3(B_N * D_N / 4 / 256), 256, 0, stream>>>(Opart, lsum, (float*)d_out);
}